// Round 1
// baseline (116.468 us; speedup 1.0000x reference)
//
#include <hip/hip_runtime.h>
#include <math.h>

// RipsH1: deaths[i] = ||points[verts0[i,0]] - points[verts0[i,1]]||  (E0 rows)
//         dgm1[i,0] = ||points[verts1[i,0]] - points[verts1[i,1]]||  (E1 rows)
//         dgm1[i,1] = ||points[verts1[i,2]] - points[verts1[i,3]]||
// Output flat: deaths (E0 floats) then dgm1 row-major (2*E1 floats).
// points: (65536, 8) f32 = 2 MB -> lives in L2 (4 MiB/XCD); gathers are L2-hits.

__device__ __forceinline__ float dist8(const float4* __restrict__ p, int ia, int ib) {
    float4 a0 = p[2 * ia];
    float4 a1 = p[2 * ia + 1];
    float4 b0 = p[2 * ib];
    float4 b1 = p[2 * ib + 1];
    float d0 = a0.x - b0.x;
    float d1 = a0.y - b0.y;
    float d2 = a0.z - b0.z;
    float d3 = a0.w - b0.w;
    float d4 = a1.x - b1.x;
    float d5 = a1.y - b1.y;
    float d6 = a1.z - b1.z;
    float d7 = a1.w - b1.w;
    float s = d0 * d0 + d1 * d1 + d2 * d2 + d3 * d3
            + d4 * d4 + d5 * d5 + d6 * d6 + d7 * d7;
    return sqrtf(s);
}

__global__ __launch_bounds__(256) void rips_kernel(
    const float* __restrict__ points,
    const int* __restrict__ verts0,
    const int* __restrict__ verts1,
    float* __restrict__ out,
    int e0, int e1) {
    int tid = blockIdx.x * blockDim.x + threadIdx.x;
    const float4* p = (const float4*)points;
    if (tid < e1) {
        // H1 pair: 16B coalesced index load, 4 gathered points, 2 results.
        int4 v = ((const int4*)verts1)[tid];
        float r0 = dist8(p, v.x, v.y);
        float r1 = dist8(p, v.z, v.w);
        out[e0 + 2 * tid]     = r0;  // dgm1 base (e0 odd) is 4B-aligned: scalar stores
        out[e0 + 2 * tid + 1] = r1;
    } else {
        int j = tid - e1;
        if (j < e0) {
            int2 v = ((const int2*)verts0)[j];
            out[j] = dist8(p, v.x, v.y);
        }
    }
}

extern "C" void kernel_launch(void* const* d_in, const int* in_sizes, int n_in,
                              void* d_out, int out_size, void* d_ws, size_t ws_size,
                              hipStream_t stream) {
    const float* points = (const float*)d_in[0];
    const int* verts0   = (const int*)d_in[1];
    const int* verts1   = (const int*)d_in[2];
    float* out = (float*)d_out;

    int e0 = in_sizes[1] / 2;  // 65535
    int e1 = in_sizes[2] / 4;  // 2000000

    int total = e1 + e0;
    int block = 256;
    int grid = (total + block - 1) / block;
    rips_kernel<<<grid, block, 0, stream>>>(points, verts0, verts1, out, e0, e1);
}

// Round 2
// 115.820 us; speedup vs baseline: 1.0056x; 1.0056x over previous
//
#include <hip/hip_runtime.h>
#include <hip/hip_fp16.h>
#include <math.h>

// RipsH1: deaths[i] = ||points[verts0[i,0]] - points[verts0[i,1]]||  (E0 rows)
//         dgm1[i,:] = ||points[verts1[i,{0,2}]] - points[verts1[i,{1,3}]]||  (E1 rows)
// Output flat: deaths (E0 floats) then dgm1 row-major (2*E1 floats).
//
// Bottleneck (round-1 rocprof): divergent vector-mem request rate, not HBM BW
// (11% peak) nor VALU (8%). Fix: convert points f32->f16 (2MB->1MB, in d_ws)
// so each gathered point is ONE global_load_dwordx4 (16B) instead of two —
// halves the scattered lane-request count 16M -> 8M.

__global__ __launch_bounds__(256) void cvt_kernel(
    const float* __restrict__ pts, __half* __restrict__ out, int n4) {
    // n4 = number of float4 groups (65536*8/4). One thread: float4 -> 4 halves.
    int i = blockIdx.x * blockDim.x + threadIdx.x;
    if (i < n4) {
        float4 f = ((const float4*)pts)[i];
        __half2 h0 = __floats2half2_rn(f.x, f.y);
        __half2 h1 = __floats2half2_rn(f.z, f.w);
        ((__half2*)out)[2 * i]     = h0;
        ((__half2*)out)[2 * i + 1] = h1;
    }
}

__device__ __forceinline__ float2 u2f2(unsigned u) {
    __half2 h = *reinterpret_cast<__half2*>(&u);
    return __half22float2(h);
}

__device__ __forceinline__ float dist8h(const uint4* __restrict__ p, int ia, int ib) {
    uint4 a = p[ia];   // one 16B scattered load = whole 8-dim fp16 point
    uint4 b = p[ib];
    float2 ax = u2f2(a.x), ay = u2f2(a.y), az = u2f2(a.z), aw = u2f2(a.w);
    float2 bx = u2f2(b.x), by = u2f2(b.y), bz = u2f2(b.z), bw = u2f2(b.w);
    float d0 = ax.x - bx.x, d1 = ax.y - bx.y;
    float d2 = ay.x - by.x, d3 = ay.y - by.y;
    float d4 = az.x - bz.x, d5 = az.y - bz.y;
    float d6 = aw.x - bw.x, d7 = aw.y - bw.y;
    float s = d0 * d0 + d1 * d1 + d2 * d2 + d3 * d3
            + d4 * d4 + d5 * d5 + d6 * d6 + d7 * d7;
    return sqrtf(s);
}

__global__ __launch_bounds__(256) void rips_kernel_h(
    const __half* __restrict__ points16,
    const int* __restrict__ verts0,
    const int* __restrict__ verts1,
    float* __restrict__ out,
    int e0, int e1) {
    int tid = blockIdx.x * blockDim.x + threadIdx.x;
    const uint4* p = (const uint4*)points16;
    if (tid < e1) {
        int4 v = ((const int4*)verts1)[tid];
        float r0 = dist8h(p, v.x, v.y);
        float r1 = dist8h(p, v.z, v.w);
        out[e0 + 2 * tid]     = r0;
        out[e0 + 2 * tid + 1] = r1;
    } else {
        int j = tid - e1;
        if (j < e0) {
            int2 v = ((const int2*)verts0)[j];
            out[j] = dist8h(p, v.x, v.y);
        }
    }
}

// Fallback (f32 gathers) in case ws is too small for the fp16 table.
__device__ __forceinline__ float dist8f(const float4* __restrict__ p, int ia, int ib) {
    float4 a0 = p[2 * ia], a1 = p[2 * ia + 1];
    float4 b0 = p[2 * ib], b1 = p[2 * ib + 1];
    float d0 = a0.x - b0.x, d1 = a0.y - b0.y, d2 = a0.z - b0.z, d3 = a0.w - b0.w;
    float d4 = a1.x - b1.x, d5 = a1.y - b1.y, d6 = a1.z - b1.z, d7 = a1.w - b1.w;
    return sqrtf(d0*d0 + d1*d1 + d2*d2 + d3*d3 + d4*d4 + d5*d5 + d6*d6 + d7*d7);
}

__global__ __launch_bounds__(256) void rips_kernel_f(
    const float* __restrict__ points,
    const int* __restrict__ verts0,
    const int* __restrict__ verts1,
    float* __restrict__ out,
    int e0, int e1) {
    int tid = blockIdx.x * blockDim.x + threadIdx.x;
    const float4* p = (const float4*)points;
    if (tid < e1) {
        int4 v = ((const int4*)verts1)[tid];
        out[e0 + 2 * tid]     = dist8f(p, v.x, v.y);
        out[e0 + 2 * tid + 1] = dist8f(p, v.z, v.w);
    } else {
        int j = tid - e1;
        if (j < e0) {
            int2 v = ((const int2*)verts0)[j];
            out[j] = dist8f(p, v.x, v.y);
        }
    }
}

extern "C" void kernel_launch(void* const* d_in, const int* in_sizes, int n_in,
                              void* d_out, int out_size, void* d_ws, size_t ws_size,
                              hipStream_t stream) {
    const float* points = (const float*)d_in[0];
    const int* verts0   = (const int*)d_in[1];
    const int* verts1   = (const int*)d_in[2];
    float* out = (float*)d_out;

    int npts_flat = in_sizes[0];       // 65536*8 floats
    int e0 = in_sizes[1] / 2;          // 65535
    int e1 = in_sizes[2] / 4;          // 2000000

    int total = e1 + e0;
    int block = 256;
    int grid = (total + block - 1) / block;

    size_t fp16_bytes = (size_t)npts_flat * sizeof(__half);
    if (ws_size >= fp16_bytes) {
        __half* p16 = (__half*)d_ws;
        int n4 = npts_flat / 4;
        cvt_kernel<<<(n4 + 255) / 256, 256, 0, stream>>>(points, p16, n4);
        rips_kernel_h<<<grid, block, 0, stream>>>(p16, verts0, verts1, out, e0, e1);
    } else {
        rips_kernel_f<<<grid, block, 0, stream>>>(points, verts0, verts1, out, e0, e1);
    }
}